// Round 2
// baseline (1450.475 us; speedup 1.0000x reference)
//
#include <hip/hip_runtime.h>
#include <hip/hip_bf16.h>

// Problem constants
#define BB 16
#define CC 256
#define HH 64
#define WW 64
#define NN 4096   // H*W
#define MM 1024   // pooled
#define C8 32
#define C2 128

__device__ __forceinline__ float bfraw(unsigned short u) {
    union { unsigned u; float f; } v; v.u = ((unsigned)u) << 16; return v.f;
}
__device__ __forceinline__ float bf(const __hip_bfloat16 x) { return __bfloat162float(x); }
__device__ __forceinline__ __hip_bfloat16 f2bf(float f) { return __float2bfloat16(f); }

union U8 { int4 v; unsigned short u[8]; };

// ---- dtype-generic element access -----------------------------------------
__device__ __forceinline__ void ld8bf(const __hip_bfloat16* s, __hip_bfloat16* d) {
    *(int4*)d = *(const int4*)s;
}
__device__ __forceinline__ void ld8bf(const float* s, __hip_bfloat16* d) {
    float4 a = *(const float4*)s; float4 b4 = *(const float4*)(s + 4);
    d[0] = f2bf(a.x); d[1] = f2bf(a.y); d[2] = f2bf(a.z); d[3] = f2bf(a.w);
    d[4] = f2bf(b4.x); d[5] = f2bf(b4.y); d[6] = f2bf(b4.z); d[7] = f2bf(b4.w);
}
__device__ __forceinline__ void ld8f(const __hip_bfloat16* s, float* f) {
    U8 u; u.v = *(const int4*)s;
    #pragma unroll
    for (int e = 0; e < 8; ++e) f[e] = bfraw(u.u[e]);
}
__device__ __forceinline__ void ld8f(const float* s, float* f) {
    float4 a = *(const float4*)s; float4 b4 = *(const float4*)(s + 4);
    f[0] = a.x; f[1] = a.y; f[2] = a.z; f[3] = a.w;
    f[4] = b4.x; f[5] = b4.y; f[6] = b4.z; f[7] = b4.w;
}
__device__ __forceinline__ float load1(const __hip_bfloat16* p) { return bf(*p); }
__device__ __forceinline__ float load1(const float* p) { return *p; }
__device__ __forceinline__ void store1(__hip_bfloat16* p, float v) { *p = f2bf(v); }
__device__ __forceinline__ void store1(float* p, float v) { *p = v; }

// ---------------------------------------------------------------------------
// dtype detection: count bf16-plausible exponent fields in 128 half-words of x
// bf16 N(0,1): ~128/128 in range.  fp32: ~75/128 (low halves are mantissa bits)
// ---------------------------------------------------------------------------
__global__ void detect_kernel(const void* x, int* flag) {
    if (threadIdx.x == 0) {
        const unsigned short* u = (const unsigned short*)x;
        int cnt = 0;
        for (int i = 0; i < 128; ++i) {
            int e = (u[i] >> 7) & 0xFF;
            if (e >= 100 && e <= 145) ++cnt;
        }
        *flag = (cnt >= 110) ? 1 : 0;   // 1 = bf16, 0 = fp32
    }
}

// ---------------------------------------------------------------------------
// Kernel A: projections theta/phi/g (+ maxpool on phi/g). Internal ws is bf16.
// ---------------------------------------------------------------------------
template<typename TI>
__global__ __launch_bounds__(256) void proj_kernel(
    const int* __restrict__ flag, int want,
    const TI* __restrict__ x,
    const TI* __restrict__ w_theta, const TI* __restrict__ b_theta,
    const TI* __restrict__ w_phi,   const TI* __restrict__ b_phi,
    const TI* __restrict__ w_g,     const TI* __restrict__ b_g,
    __hip_bfloat16* __restrict__ theta_t,
    __hip_bfloat16* __restrict__ phi,
    __hip_bfloat16* __restrict__ g)
{
    if (*flag != want) return;

    __shared__ __hip_bfloat16 xt[256 * 128];   // [c][p]
    __shared__ __hip_bfloat16 ot[192 * 130];   // [r][p], pad 130

    const int t  = threadIdx.x;
    const int b  = blockIdx.x >> 5;
    const int ph = blockIdx.x & 31;

    const TI* xb = x + (size_t)b * CC * NN + ph * 128;

    // ---- load x tile: 256 rows x 128 pos
    #pragma unroll
    for (int i = 0; i < 16; ++i) {
        int chunk = i * 256 + t;
        int c  = chunk >> 4;
        int p0 = (chunk & 15) * 8;
        ld8bf(xb + (size_t)c * NN + p0, &xt[c * 128 + p0]);
    }
    __syncthreads();

    // ---- compute 192x128 conv outputs; 4 rows share each x read
    #pragma unroll 1
    for (int i = 0; i < 24; ++i) {
        int oidx = i * 256 + t;
        int p  = oidx & 127;
        int br = oidx >> 7;              // 0..47
        const TI* wp[4];
        float acc[4];
        #pragma unroll
        for (int j = 0; j < 4; ++j) {
            int r = br + 48 * j;
            if (r < 32)       { wp[j] = w_theta + r * CC;        acc[j] = load1(b_theta + r); }
            else if (r < 64)  { wp[j] = w_phi + (r - 32) * CC;   acc[j] = load1(b_phi + r - 32); }
            else              { wp[j] = w_g + (r - 64) * CC;     acc[j] = load1(b_g + r - 64); }
        }
        #pragma unroll 4
        for (int c0 = 0; c0 < CC; c0 += 8) {
            float xv[8];
            #pragma unroll
            for (int e = 0; e < 8; ++e) xv[e] = bf(xt[(c0 + e) * 128 + p]);
            #pragma unroll
            for (int j = 0; j < 4; ++j) {
                float wv[8];
                ld8f(wp[j] + c0, wv);
                #pragma unroll
                for (int e = 0; e < 8; ++e) acc[j] += wv[e] * xv[e];
            }
        }
        #pragma unroll
        for (int j = 0; j < 4; ++j) {
            int r = br + 48 * j;
            ot[r * 130 + p] = f2bf(acc[j]);
        }
    }
    __syncthreads();

    // ---- theta: transposed coalesced write [n][c]
    const size_t tbase = ((size_t)b * NN + ph * 128) * C8;
    #pragma unroll
    for (int i = 0; i < 16; ++i) {
        int idx = i * 256 + t;
        int p = idx >> 5;
        int r = idx & 31;
        theta_t[tbase + (size_t)p * C8 + r] = ot[r * 130 + p];
    }
    // ---- phi pooled (rows 32..63)
    #pragma unroll
    for (int i = 0; i < 4; ++i) {
        int idx = i * 256 + t;
        int r  = idx >> 5;
        int pw = idx & 31;
        int rr = 32 + r;
        float v0 = bf(ot[rr * 130 + 2 * pw]);
        float v1 = bf(ot[rr * 130 + 2 * pw + 1]);
        float v2 = bf(ot[rr * 130 + 64 + 2 * pw]);
        float v3 = bf(ot[rr * 130 + 64 + 2 * pw + 1]);
        float mx = fmaxf(fmaxf(v0, v1), fmaxf(v2, v3));
        phi[((size_t)b * C8 + r) * MM + ph * 32 + pw] = f2bf(mx);
    }
    // ---- g pooled (rows 64..191)
    #pragma unroll
    for (int i = 0; i < 16; ++i) {
        int idx = i * 256 + t;
        int r  = idx >> 5;
        int pw = idx & 31;
        int rr = 64 + r;
        float v0 = bf(ot[rr * 130 + 2 * pw]);
        float v1 = bf(ot[rr * 130 + 2 * pw + 1]);
        float v2 = bf(ot[rr * 130 + 64 + 2 * pw]);
        float v3 = bf(ot[rr * 130 + 64 + 2 * pw + 1]);
        float mx = fmaxf(fmaxf(v0, v1), fmaxf(v2, v3));
        g[((size_t)b * C2 + r) * MM + ph * 32 + pw] = f2bf(mx);
    }
}

// ---------------------------------------------------------------------------
// Kernel B: flash attention (all inputs are internal bf16 ws — runs once)
// ---------------------------------------------------------------------------
__global__ __launch_bounds__(256) void attn_kernel(
    const __hip_bfloat16* __restrict__ theta_t,
    const __hip_bfloat16* __restrict__ phi,
    const __hip_bfloat16* __restrict__ g,
    __hip_bfloat16* __restrict__ o_pre)
{
    __shared__ __hip_bfloat16 phs[32 * 128];   // [c][m]
    __shared__ __hip_bfloat16 gs[128 * 136];   // [c][m] pad 136
    __shared__ float st[32 * 130];             // [q][m] scores / [q][c] staging
    __shared__ __hip_bfloat16 ths[32 * 32];    // [q][c]
    __shared__ float red1[32 * 8];
    __shared__ float red2[32 * 8];

    const int t  = threadIdx.x;
    const int b  = blockIdx.x >> 7;
    const int qt = blockIdx.x & 127;
    const int nbase = qt * 32;
    const int q  = t >> 3;
    const int ms = t & 7;

    if (t < 128) {
        int4 v = *(const int4*)(theta_t + ((size_t)b * NN + nbase) * C8 + t * 8);
        *(int4*)(&ths[t * 8]) = v;
    }
    __syncthreads();

    float th[32];
    #pragma unroll
    for (int c = 0; c < 32; ++c) th[c] = bf(ths[q * 32 + c]);

    float m_run = -1e30f, l_run = 0.f;
    float oa[16];
    #pragma unroll
    for (int k = 0; k < 16; ++k) oa[k] = 0.f;

    const __hip_bfloat16* phb = phi + (size_t)b * C8 * MM;
    const __hip_bfloat16* gb  = g + (size_t)b * C2 * MM;
    float* strow = &st[q * 130];

    for (int kt = 0; kt < 8; ++kt) {
        const int mb = kt * 128;
        __syncthreads();
        #pragma unroll
        for (int i = 0; i < 2; ++i) {
            int chunk = i * 256 + t;
            int c  = chunk >> 4;
            int m0 = (chunk & 15) * 8;
            *(int4*)(&phs[c * 128 + m0]) = *(const int4*)(phb + (size_t)c * MM + mb + m0);
        }
        #pragma unroll
        for (int i = 0; i < 8; ++i) {
            int chunk = i * 256 + t;
            int c  = chunk >> 4;
            int m0 = (chunk & 15) * 8;
            *(int4*)(&gs[c * 136 + m0]) = *(const int4*)(gb + (size_t)c * MM + mb + m0);
        }
        __syncthreads();

        float sv[16];
        float lmax = -1e30f;
        #pragma unroll
        for (int mi = 0; mi < 16; mi += 2) {
            int mm = ms * 16 + mi;
            float a0 = 0.f, a1 = 0.f;
            #pragma unroll
            for (int c = 0; c < 32; ++c) {
                unsigned pp = *(const unsigned*)(&phs[c * 128 + mm]);
                a0 += th[c] * bfraw((unsigned short)(pp & 0xffff));
                a1 += th[c] * bfraw((unsigned short)(pp >> 16));
            }
            sv[mi] = a0; sv[mi + 1] = a1;
            lmax = fmaxf(lmax, fmaxf(a0, a1));
        }
        red1[q * 8 + ms] = lmax;
        __syncthreads();

        float tmax = red1[q * 8];
        #pragma unroll
        for (int j = 1; j < 8; ++j) tmax = fmaxf(tmax, red1[q * 8 + j]);
        float nm = fmaxf(m_run, tmax);
        float scale = __expf(m_run - nm);
        float ls = 0.f;
        #pragma unroll
        for (int mi = 0; mi < 16; ++mi) {
            float p = __expf(sv[mi] - nm);
            ls += p;
            strow[ms * 16 + mi] = p;
        }
        red2[q * 8 + ms] = ls;
        __syncthreads();

        float lt = 0.f;
        #pragma unroll
        for (int j = 0; j < 8; ++j) lt += red2[q * 8 + j];
        l_run = l_run * scale + lt;
        m_run = nm;
        #pragma unroll
        for (int k = 0; k < 16; ++k) oa[k] *= scale;

        #pragma unroll 4
        for (int m = 0; m < 128; m += 2) {
            float2 bb2 = *(const float2*)(&strow[m]);
            #pragma unroll
            for (int k = 0; k < 16; ++k) {
                int c = ms + 8 * k;
                unsigned gp = *(const unsigned*)(&gs[c * 136 + m]);
                oa[k] += bb2.x * bfraw((unsigned short)(gp & 0xffff))
                       + bb2.y * bfraw((unsigned short)(gp >> 16));
            }
        }
    }

    float inv = 1.f / l_run;
    __syncthreads();
    #pragma unroll
    for (int k = 0; k < 16; ++k) st[q * 130 + ms + 8 * k] = oa[k] * inv;
    __syncthreads();
    #pragma unroll
    for (int i = 0; i < 16; ++i) {
        int idx = i * 256 + t;
        int c  = idx >> 5;
        int qq = idx & 31;
        o_pre[((size_t)b * C2 + c) * NN + nbase + qq] = f2bf(st[qq * 130 + c]);
    }
}

// ---------------------------------------------------------------------------
// Kernel C: o = W_o * o_pre + b_o ; out = gamma*o + x
// ---------------------------------------------------------------------------
template<typename TI>
__global__ __launch_bounds__(256) void out_kernel(
    const int* __restrict__ flag, int want,
    const __hip_bfloat16* __restrict__ o_pre,
    const TI* __restrict__ w_o, const TI* __restrict__ b_o,
    const TI* __restrict__ x,
    const TI* __restrict__ gamma,
    TI* __restrict__ out)
{
    if (*flag != want) return;

    __shared__ __hip_bfloat16 ops[128 * 128];  // [c2][p]

    const int t  = threadIdx.x;
    const int b  = blockIdx.x >> 5;
    const int pt = blockIdx.x & 31;
    const int pbase = pt * 128;

    #pragma unroll
    for (int i = 0; i < 8; ++i) {
        int chunk = i * 256 + t;
        int c  = chunk >> 4;
        int p0 = (chunk & 15) * 8;
        *(int4*)(&ops[c * 128 + p0]) =
            *(const int4*)(o_pre + ((size_t)b * C2 + c) * NN + pbase + p0);
    }
    __syncthreads();

    const float gam = load1(gamma);

    #pragma unroll 1
    for (int i = 0; i < 64; ++i) {
        int idx = i * 256 + t;
        int p  = idx & 127;
        int co = idx >> 7;   // 0..127; also handles co+128
        float acc0 = load1(b_o + co);
        float acc1 = load1(b_o + co + 128);
        #pragma unroll 4
        for (int c0 = 0; c0 < C2; c0 += 8) {
            float xv[8];
            #pragma unroll
            for (int e = 0; e < 8; ++e) xv[e] = bf(ops[(c0 + e) * 128 + p]);
            float w0[8], w1[8];
            ld8f(w_o + co * C2 + c0, w0);
            ld8f(w_o + (co + 128) * C2 + c0, w1);
            #pragma unroll
            for (int e = 0; e < 8; ++e) {
                acc0 += w0[e] * xv[e];
                acc1 += w1[e] * xv[e];
            }
        }
        size_t o0 = ((size_t)b * CC + co) * NN + pbase + p;
        size_t o1 = ((size_t)b * CC + co + 128) * NN + pbase + p;
        store1(out + o0, gam * acc0 + load1(x + o0));
        store1(out + o1, gam * acc1 + load1(x + o1));
    }
}

// ---------------------------------------------------------------------------
extern "C" void kernel_launch(void* const* d_in, const int* in_sizes, int n_in,
                              void* d_out, int out_size, void* d_ws, size_t ws_size,
                              hipStream_t stream)
{
    char* ws = (char*)d_ws;
    int* flag = (int*)ws;                                               // 4 B @ 0
    __hip_bfloat16* theta_t = (__hip_bfloat16*)(ws + (1u << 20));       // 4 MB  [B][N][32]
    __hip_bfloat16* phi     = (__hip_bfloat16*)(ws + (5u << 20));       // 1 MB  [B][32][M]
    __hip_bfloat16* g       = (__hip_bfloat16*)(ws + (6u << 20));       // 4 MB  [B][128][M]
    __hip_bfloat16* o_pre   = (__hip_bfloat16*)(ws + (10u << 20));      // 16 MB [B][128][N]

    detect_kernel<<<1, 64, 0, stream>>>(d_in[0], flag);

    // bf16 variant
    proj_kernel<__hip_bfloat16><<<BB * 32, 256, 0, stream>>>(
        flag, 1,
        (const __hip_bfloat16*)d_in[0],
        (const __hip_bfloat16*)d_in[1], (const __hip_bfloat16*)d_in[2],
        (const __hip_bfloat16*)d_in[3], (const __hip_bfloat16*)d_in[4],
        (const __hip_bfloat16*)d_in[5], (const __hip_bfloat16*)d_in[6],
        theta_t, phi, g);
    // fp32 variant
    proj_kernel<float><<<BB * 32, 256, 0, stream>>>(
        flag, 0,
        (const float*)d_in[0],
        (const float*)d_in[1], (const float*)d_in[2],
        (const float*)d_in[3], (const float*)d_in[4],
        (const float*)d_in[5], (const float*)d_in[6],
        theta_t, phi, g);

    attn_kernel<<<BB * 128, 256, 0, stream>>>(theta_t, phi, g, o_pre);

    out_kernel<__hip_bfloat16><<<BB * 32, 256, 0, stream>>>(
        flag, 1, o_pre,
        (const __hip_bfloat16*)d_in[7], (const __hip_bfloat16*)d_in[8],
        (const __hip_bfloat16*)d_in[0], (const __hip_bfloat16*)d_in[9],
        (__hip_bfloat16*)d_out);
    out_kernel<float><<<BB * 32, 256, 0, stream>>>(
        flag, 0, o_pre,
        (const float*)d_in[7], (const float*)d_in[8],
        (const float*)d_in[0], (const float*)d_in[9],
        (float*)d_out);
}

// Round 3
// 293.183 us; speedup vs baseline: 4.9473x; 4.9473x over previous
//
#include <hip/hip_runtime.h>
#include <hip/hip_bf16.h>

#define BB 16
#define NN 4096
#define MM 1024

typedef __attribute__((ext_vector_type(8))) short bf16x8;
typedef __attribute__((ext_vector_type(4))) float f32x4;

__device__ __forceinline__ unsigned short f2bfbits(float f) {
    union { float f; unsigned u; } v; v.f = f;
    unsigned r = v.u + 0x7fffu + ((v.u >> 16) & 1u);   // RNE
    return (unsigned short)(r >> 16);
}
__device__ __forceinline__ float bfraw(unsigned short u) {
    union { unsigned u; float f; } v; v.u = ((unsigned)u) << 16; return v.f;
}

// ---------------------------------------------------------------------------
// prep: fp32 params -> bf16 ws copies. w_all=[theta;phi;g] [192][256],
// w_o_bf [256][128], b_all fp32 [192].
// ---------------------------------------------------------------------------
__global__ void prep_kernel(
    const float* __restrict__ wt, const float* __restrict__ bt,
    const float* __restrict__ wp, const float* __restrict__ bp,
    const float* __restrict__ wg, const float* __restrict__ bg,
    const float* __restrict__ wo,
    unsigned short* __restrict__ w_all, unsigned short* __restrict__ w_o_bf,
    float* __restrict__ b_all)
{
    int i = blockIdx.x * 256 + threadIdx.x;
    if (i < 8192)        w_all[i] = f2bfbits(wt[i]);
    else if (i < 16384)  w_all[i] = f2bfbits(wp[i - 8192]);
    else if (i < 49152)  w_all[i] = f2bfbits(wg[i - 16384]);
    else if (i < 81920)  w_o_bf[i - 49152] = f2bfbits(wo[i - 49152]);
    else if (i < 82112) {
        int r = i - 81920;
        b_all[r] = (r < 32) ? bt[r] : (r < 64) ? bp[r - 32] : bg[r - 64];
    }
}

// ---------------------------------------------------------------------------
// proj: [192 co] x [256 cin] GEMM over 128 positions per block, + bias,
// theta transpose-out, 2x2 maxpool for phi/g. MFMA 16x16x32 bf16.
// block: 256 thr (4 waves), wave w owns co-tiles {3w,3w+1,3w+2}.
// ---------------------------------------------------------------------------
__global__ __launch_bounds__(256, 2) void proj_kernel(
    const float* __restrict__ x,
    const unsigned short* __restrict__ w_all,
    const float* __restrict__ b_all,
    unsigned short* __restrict__ theta_t,   // [B][4096][32]
    unsigned short* __restrict__ phi_t,     // [B][1024][32]
    unsigned short* __restrict__ g)         // [B][128][1024]
{
    __shared__ unsigned short ot[192 * 136];   // [co][pos] pad 136

    const int t = threadIdx.x;
    const int w = t >> 6;
    const int l = t & 63;
    const int lr = l & 15, lg = l >> 4;
    const int b  = blockIdx.x >> 5;
    const int pt = blockIdx.x & 31;
    const int pbase = pt << 7;      // 128 positions = 2 image rows
    const int mb = pt << 5;         // 32 pooled positions

    f32x4 acc[3][8];
    #pragma unroll
    for (int i = 0; i < 3; ++i)
        #pragma unroll
        for (int nt = 0; nt < 8; ++nt) acc[i][nt] = (f32x4){0.f,0.f,0.f,0.f};

    const float* xb = x + (size_t)b * 256 * 4096 + pbase + lr;

    #pragma unroll 1
    for (int ks = 0; ks < 8; ++ks) {
        bf16x8 af[3];
        #pragma unroll
        for (int i = 0; i < 3; ++i)
            af[i] = *(const bf16x8*)(w_all + (size_t)(16*(3*w+i) + lr)*256 + 32*ks + 8*lg);
        #pragma unroll
        for (int nt = 0; nt < 8; ++nt) {
            const float* xp = xb + 16*nt + (size_t)(32*ks + 8*lg) * 4096;
            union { bf16x8 v; unsigned short u[8]; } bx;
            #pragma unroll
            for (int j = 0; j < 8; ++j) bx.u[j] = f2bfbits(xp[(size_t)j * 4096]);
            #pragma unroll
            for (int i = 0; i < 3; ++i)
                acc[i][nt] = __builtin_amdgcn_mfma_f32_16x16x32_bf16(af[i], bx.v, acc[i][nt], 0, 0, 0);
        }
    }

    // stage frags (+bias) to LDS: D row = co-in-tile = 4*lg+r, col = pos = lr
    float bias[3][4];
    #pragma unroll
    for (int i = 0; i < 3; ++i)
        #pragma unroll
        for (int r = 0; r < 4; ++r) bias[i][r] = b_all[16*(3*w+i) + 4*lg + r];
    #pragma unroll
    for (int i = 0; i < 3; ++i)
        #pragma unroll
        for (int nt = 0; nt < 8; ++nt)
            #pragma unroll
            for (int r = 0; r < 4; ++r)
                ot[(16*(3*w+i) + 4*lg + r)*136 + 16*nt + lr] =
                    f2bfbits(acc[i][nt][r] + bias[i][r]);
    __syncthreads();

    // theta rows 0..31 -> theta_t[b][n][32] (transposed, coalesced 64B/row)
    if (t < 128) {
        int p = t;
        union { unsigned short u[32]; int4 v[4]; } th;
        #pragma unroll
        for (int c = 0; c < 32; ++c) th.u[c] = ot[c*136 + p];
        int4* dst = (int4*)(theta_t + ((size_t)(b*4096 + pbase + p)) * 32);
        #pragma unroll
        for (int q = 0; q < 4; ++q) dst[q] = th.v[q];
    }
    // phi pooled (ot rows 32..63) -> phi_t[b][m][32]
    {
        int ww = t >> 3, c0 = (t & 7) * 4;
        union { unsigned short u[4]; int2 v; } ph;
        #pragma unroll
        for (int e = 0; e < 4; ++e) {
            int row = 32 + c0 + e;
            unsigned p01 = *(const unsigned*)&ot[row*136 + 2*ww];
            unsigned p23 = *(const unsigned*)&ot[row*136 + 64 + 2*ww];
            float m0 = fmaxf(bfraw((unsigned short)p01), bfraw((unsigned short)(p01 >> 16)));
            float m1 = fmaxf(bfraw((unsigned short)p23), bfraw((unsigned short)(p23 >> 16)));
            ph.u[e] = f2bfbits(fmaxf(m0, m1));
        }
        *(int2*)(phi_t + ((size_t)(b*1024 + mb + ww)) * 32 + c0) = ph.v;
    }
    // g pooled (ot rows 64..191) -> g[b][c2][1024]
    {
        int c2 = t >> 1, w0 = (t & 1) * 16;
        int row = 64 + c2;
        union { unsigned short u[16]; int4 v[2]; } gv;
        #pragma unroll
        for (int e = 0; e < 16; ++e) {
            int ww = w0 + e;
            unsigned p01 = *(const unsigned*)&ot[row*136 + 2*ww];
            unsigned p23 = *(const unsigned*)&ot[row*136 + 64 + 2*ww];
            float m0 = fmaxf(bfraw((unsigned short)p01), bfraw((unsigned short)(p01 >> 16)));
            float m1 = fmaxf(bfraw((unsigned short)p23), bfraw((unsigned short)(p23 >> 16)));
            gv.u[e] = f2bfbits(fmaxf(m0, m1));
        }
        int4* dst = (int4*)(g + ((size_t)(b*128 + c2)) * 1024 + mb + w0);
        dst[0] = gv.v[0]; dst[1] = gv.v[1];
    }
}

// ---------------------------------------------------------------------------
// attn: 1 wave per block, 32 queries x 1024 keys, key-chunks of 64.
// QK^T + online softmax + PV, all MFMA. Writes o_pre_t [B][4096][128].
// ---------------------------------------------------------------------------
__global__ __launch_bounds__(64, 2) void attn_kernel(
    const unsigned short* __restrict__ theta_t,
    const unsigned short* __restrict__ phi_t,
    const unsigned short* __restrict__ g,
    unsigned short* __restrict__ o_pre_t)
{
    __shared__ unsigned short plds[32 * 72];    // P tile [q][64m] pad 72
    __shared__ unsigned short olds[32 * 136];   // out stage [q][128c] pad 136

    const int l = threadIdx.x;
    const int lr = l & 15, lg = l >> 4;
    const int b  = blockIdx.x >> 7;
    const int nb = (blockIdx.x & 127) << 5;

    const f32x4 zero = {0.f, 0.f, 0.f, 0.f};

    bf16x8 aq[2];
    #pragma unroll
    for (int qt = 0; qt < 2; ++qt)
        aq[qt] = *(const bf16x8*)(theta_t + ((size_t)(b*4096 + nb + 16*qt + lr))*32 + 8*lg);

    f32x4 po[2][8];
    #pragma unroll
    for (int qt = 0; qt < 2; ++qt)
        #pragma unroll
        for (int ct = 0; ct < 8; ++ct) po[qt][ct] = zero;
    float mr[2][4], lrun[2][4];
    #pragma unroll
    for (int qt = 0; qt < 2; ++qt)
        #pragma unroll
        for (int r = 0; r < 4; ++r) { mr[qt][r] = -1e30f; lrun[qt][r] = 0.f; }

    const unsigned short* phb = phi_t + (size_t)b * 1024 * 32;
    const unsigned short* gb  = g + (size_t)b * 128 * 1024;

    #pragma unroll 1
    for (int kt = 0; kt < 16; ++kt) {
        const int mb = kt * 64;
        // ---- QK^T: 8 MFMAs (2 qt x 4 mt), K=32 in one shot
        f32x4 s[2][4];
        #pragma unroll
        for (int mt = 0; mt < 4; ++mt) {
            bf16x8 bp = *(const bf16x8*)(phb + (size_t)(mb + 16*mt + lr)*32 + 8*lg);
            s[0][mt] = __builtin_amdgcn_mfma_f32_16x16x32_bf16(aq[0], bp, zero, 0, 0, 0);
            s[1][mt] = __builtin_amdgcn_mfma_f32_16x16x32_bf16(aq[1], bp, zero, 0, 0, 0);
        }
        // ---- online softmax: rows q=(lg*4+r), cols m across 16 lanes + 4 mt
        float sc[2][4];
        #pragma unroll
        for (int qt = 0; qt < 2; ++qt)
            #pragma unroll
            for (int r = 0; r < 4; ++r) {
                float mx = fmaxf(fmaxf(s[qt][0][r], s[qt][1][r]),
                                 fmaxf(s[qt][2][r], s[qt][3][r]));
                #pragma unroll
                for (int msk = 1; msk < 16; msk <<= 1) mx = fmaxf(mx, __shfl_xor(mx, msk));
                float nm  = fmaxf(mr[qt][r], mx);
                float scv = __expf(mr[qt][r] - nm);
                mr[qt][r] = nm; sc[qt][r] = scv;
                float ls = 0.f;
                #pragma unroll
                for (int mt = 0; mt < 4; ++mt) {
                    float p = __expf(s[qt][mt][r] - nm);
                    s[qt][mt][r] = p; ls += p;
                }
                #pragma unroll
                for (int msk = 1; msk < 16; msk <<= 1) ls += __shfl_xor(ls, msk);
                lrun[qt][r] = lrun[qt][r] * scv + ls;
            }
        #pragma unroll
        for (int qt = 0; qt < 2; ++qt)
            #pragma unroll
            for (int ct = 0; ct < 8; ++ct)
                #pragma unroll
                for (int r = 0; r < 4; ++r) po[qt][ct][r] *= sc[qt][r];
        // ---- P -> LDS (bf16)
        #pragma unroll
        for (int qt = 0; qt < 2; ++qt)
            #pragma unroll
            for (int mt = 0; mt < 4; ++mt)
                #pragma unroll
                for (int r = 0; r < 4; ++r)
                    plds[(16*qt + 4*lg + r)*72 + 16*mt + lr] = f2bfbits(s[qt][mt][r]);
        // ---- PV: 32 MFMAs (2 ks x 8 ct x 2 qt)
        #pragma unroll
        for (int ks = 0; ks < 2; ++ks) {
            bf16x8 pa0 = *(const bf16x8*)(plds + (size_t)lr*72 + 32*ks + 8*lg);
            bf16x8 pa1 = *(const bf16x8*)(plds + (size_t)(16 + lr)*72 + 32*ks + 8*lg);
            #pragma unroll
            for (int ct = 0; ct < 8; ++ct) {
                bf16x8 bg = *(const bf16x8*)(gb + (size_t)(16*ct + lr)*1024 + mb + 32*ks + 8*lg);
                po[0][ct] = __builtin_amdgcn_mfma_f32_16x16x32_bf16(pa0, bg, po[0][ct], 0, 0, 0);
                po[1][ct] = __builtin_amdgcn_mfma_f32_16x16x32_bf16(pa1, bg, po[1][ct], 0, 0, 0);
            }
        }
    }

    // ---- normalize + stage + coalesced write (single wave: no barriers needed)
    float inv[2][4];
    #pragma unroll
    for (int qt = 0; qt < 2; ++qt)
        #pragma unroll
        for (int r = 0; r < 4; ++r) inv[qt][r] = 1.f / lrun[qt][r];
    #pragma unroll
    for (int qt = 0; qt < 2; ++qt)
        #pragma unroll
        for (int ct = 0; ct < 8; ++ct)
            #pragma unroll
            for (int r = 0; r < 4; ++r)
                olds[(16*qt + 4*lg + r)*136 + 16*ct + lr] =
                    f2bfbits(po[qt][ct][r] * inv[qt][r]);
    #pragma unroll
    for (int i = 0; i < 8; ++i) {
        int idx = i * 64 + l;
        int q = idx >> 4, ch = idx & 15;
        int4 v = *(const int4*)(olds + q*136 + 8*ch);
        *(int4*)(o_pre_t + ((size_t)(b*4096 + nb + q))*128 + 8*ch) = v;
    }
}

// ---------------------------------------------------------------------------
// out: GEMM [256 co] x [128 c2] x [64 n per block] + gamma*o + x residual.
// ---------------------------------------------------------------------------
__global__ __launch_bounds__(256, 2) void out_kernel(
    const unsigned short* __restrict__ o_pre_t,
    const unsigned short* __restrict__ w_o_bf,
    const float* __restrict__ b_o,
    const float* __restrict__ x,
    const float* __restrict__ gamma,
    float* __restrict__ out)
{
    const int t = threadIdx.x;
    const int w = t >> 6, l = t & 63;
    const int lr = l & 15, lg = l >> 4;
    const int b   = blockIdx.x >> 6;
    const int nbv = (blockIdx.x & 63) << 6;

    f32x4 acc[4][4];
    #pragma unroll
    for (int i = 0; i < 4; ++i)
        #pragma unroll
        for (int nt = 0; nt < 4; ++nt) acc[i][nt] = (f32x4){0.f,0.f,0.f,0.f};

    #pragma unroll 1
    for (int ks = 0; ks < 4; ++ks) {
        bf16x8 aw[4], bo[4];
        #pragma unroll
        for (int i = 0; i < 4; ++i)
            aw[i] = *(const bf16x8*)(w_o_bf + (size_t)(16*(4*w+i) + lr)*128 + 32*ks + 8*lg);
        #pragma unroll
        for (int nt = 0; nt < 4; ++nt)
            bo[nt] = *(const bf16x8*)(o_pre_t + ((size_t)(b*4096 + nbv + 16*nt + lr))*128 + 32*ks + 8*lg);
        #pragma unroll
        for (int i = 0; i < 4; ++i)
            #pragma unroll
            for (int nt = 0; nt < 4; ++nt)
                acc[i][nt] = __builtin_amdgcn_mfma_f32_16x16x32_bf16(aw[i], bo[nt], acc[i][nt], 0, 0, 0);
    }

    const float gam = gamma[0];
    float bias[4][4];
    #pragma unroll
    for (int i = 0; i < 4; ++i)
        #pragma unroll
        for (int r = 0; r < 4; ++r) bias[i][r] = b_o[16*(4*w+i) + 4*lg + r];

    #pragma unroll
    for (int i = 0; i < 4; ++i)
        #pragma unroll
        for (int nt = 0; nt < 4; ++nt)
            #pragma unroll
            for (int r = 0; r < 4; ++r) {
                int co = 16*(4*w+i) + 4*lg + r;
                int n  = nbv + 16*nt + lr;
                size_t off = ((size_t)(b*256 + co)) * 4096 + n;
                out[off] = gam * (acc[i][nt][r] + bias[i][r]) + x[off];
            }
}

// ---------------------------------------------------------------------------
extern "C" void kernel_launch(void* const* d_in, const int* in_sizes, int n_in,
                              void* d_out, int out_size, void* d_ws, size_t ws_size,
                              hipStream_t stream)
{
    const float* x       = (const float*)d_in[0];
    const float* w_theta = (const float*)d_in[1];
    const float* b_theta = (const float*)d_in[2];
    const float* w_phi   = (const float*)d_in[3];
    const float* b_phi   = (const float*)d_in[4];
    const float* w_g     = (const float*)d_in[5];
    const float* b_g     = (const float*)d_in[6];
    const float* w_o     = (const float*)d_in[7];
    const float* b_o     = (const float*)d_in[8];
    const float* gamma   = (const float*)d_in[9];
    float* outp = (float*)d_out;

    char* ws = (char*)d_ws;
    unsigned short* w_all   = (unsigned short*)ws;                  // 96 KB
    unsigned short* w_o_bf  = (unsigned short*)(ws + 98304);        // 64 KB
    float*          b_all   = (float*)(ws + 163840);                // 768 B
    unsigned short* theta_t = (unsigned short*)(ws + (1u << 20));   // 4 MB [B][4096][32]
    unsigned short* phi_t   = (unsigned short*)(ws + (5u << 20));   // 1 MB [B][1024][32]
    unsigned short* g       = (unsigned short*)(ws + (6u << 20));   // 4 MB [B][128][1024]
    unsigned short* o_pre_t = (unsigned short*)(ws + (10u << 20));  // 16 MB [B][4096][128]

    prep_kernel<<<321, 256, 0, stream>>>(w_theta, b_theta, w_phi, b_phi,
                                         w_g, b_g, w_o, w_all, w_o_bf, b_all);
    proj_kernel<<<BB * 32, 256, 0, stream>>>(x, w_all, b_all, theta_t, phi_t, g);
    attn_kernel<<<BB * 128, 64, 0, stream>>>(theta_t, phi_t, g, o_pre_t);
    out_kernel<<<BB * 64, 256, 0, stream>>>(o_pre_t, w_o_bf, b_o, x, gamma, outp);
}